// Round 1
// baseline (585.431 us; speedup 1.0000x reference)
//
#include <hip/hip_runtime.h>

#define LN_EPS 1e-5f

static __device__ __forceinline__ float4 ld4(const float* p){ return *(const float4*)p; }

// ---------------- edge format detect + extract ----------------
// flag=1 -> int32 layout; flag=0 -> int64 little-endian layout
__global__ void detect_fmt_kernel(const int* __restrict__ ei, int* __restrict__ flag){
  __shared__ int any;
  if (threadIdx.x == 0) any = 0;
  __syncthreads();
  int nz = 0;
  for (int i = threadIdx.x; i < 1024; i += 256)
    nz |= (ei[2*i+1] != 0);
  if (nz) atomicOr(&any, 1);
  __syncthreads();
  if (threadIdx.x == 0) *flag = any;
}

__global__ void extract_edges_kernel(const int* __restrict__ ei, int E,
                                     const int* __restrict__ flag,
                                     int* __restrict__ src, int* __restrict__ dst){
  int e = blockIdx.x*256 + threadIdx.x;
  if (e >= E) return;
  if (*flag){           // int32 [2][E]
    src[e] = ei[e];
    dst[e] = ei[E + e];
  } else {              // int64 [2][E], values < 2^31 so low word suffices
    src[e] = ei[2*e];
    dst[e] = ei[2*(E + e)];
  }
}

// ---------------- CSR build ----------------
__global__ void count_deg_kernel(const int* __restrict__ dst, int* __restrict__ deg, int E){
  int e = blockIdx.x*256 + threadIdx.x;
  if (e < E) atomicAdd(&deg[dst[e]], 1);
}

__global__ __launch_bounds__(1024) void scan_kernel(const int* __restrict__ deg,
                                                    int* __restrict__ row_start,
                                                    int* __restrict__ cursor, int n){
  const int C = (n + 1023) >> 10;
  int t = threadIdx.x;
  int lo = t*C, hi = min(lo + C, n);
  int s = 0;
  for (int i = lo; i < hi; i++) s += deg[i];
  __shared__ int sm[1024];
  sm[t] = s;
  __syncthreads();
  for (int off = 1; off < 1024; off <<= 1){
    int v = (t >= off) ? sm[t-off] : 0;
    __syncthreads();
    sm[t] += v;
    __syncthreads();
  }
  int run = sm[t] - s;      // exclusive prefix of this thread's chunk
  for (int i = lo; i < hi; i++){
    int d = deg[i];
    row_start[i] = run;
    cursor[i] = run;
    run += d;
  }
}

__global__ void scatter_kernel(const int* __restrict__ src, const int* __restrict__ dst,
                               int* __restrict__ cursor, int* __restrict__ csr, int E){
  int e = blockIdx.x*256 + threadIdx.x;
  if (e >= E) return;
  int d = dst[e];
  int p = atomicAdd(&cursor[d], 1);
  csr[p] = src[e];
}

// ---------------- segmented mean (1 wave per node) ----------------
__global__ __launch_bounds__(256) void aggregate_kernel(const float* __restrict__ h,
    const int* __restrict__ csr, const int* __restrict__ row_start,
    const int* __restrict__ deg, float* __restrict__ outmean, int N){
  int node = blockIdx.x*4 + (threadIdx.x >> 6);
  if (node >= N) return;
  int lane = threadIdx.x & 63;
  int start = row_start[node];
  int d = deg[node];
  float ax = 0.f, ay = 0.f;
  int e = 0;
  for (; e + 4 <= d; e += 4){
    int j0 = csr[start+e+0], j1 = csr[start+e+1];
    int j2 = csr[start+e+2], j3 = csr[start+e+3];
    float2 v0 = *(const float2*)(h + (size_t)j0*128 + lane*2);
    float2 v1 = *(const float2*)(h + (size_t)j1*128 + lane*2);
    float2 v2 = *(const float2*)(h + (size_t)j2*128 + lane*2);
    float2 v3 = *(const float2*)(h + (size_t)j3*128 + lane*2);
    ax += v0.x + v1.x + v2.x + v3.x;
    ay += v0.y + v1.y + v2.y + v3.y;
  }
  for (; e < d; e++){
    int j = csr[start+e];
    float2 v = *(const float2*)(h + (size_t)j*128 + lane*2);
    ax += v.x; ay += v.y;
  }
  float inv = 1.f / fmaxf((float)d, 1.f);
  float2 r; r.x = ax*inv; r.y = ay*inv;
  *(float2*)(outmean + (size_t)node*128 + lane*2) = r;
}

// ---------------- dual GEMM: out = A1@W1^T + A2@W2^T + bias, + LN stats ----------------
__global__ __launch_bounds__(256) void gemm_dual_kernel(
    const float* __restrict__ A1, const float* __restrict__ A2,
    const float* __restrict__ W1, const float* __restrict__ W2,
    const float* __restrict__ bias,
    float* __restrict__ out, int N, double* __restrict__ stats){
  __shared__ float A1s[64][32];
  __shared__ float A2s[64][32];
  __shared__ float W1t[32][132];
  __shared__ float W2t[32][132];

  const int tid = threadIdx.x;
  const int cg  = tid & 31;      // cols 4cg..4cg+3
  const int rs  = tid >> 5;      // 0..7, rows rs+8m
  const int row0 = blockIdx.x * 64;

  float4 acc[8];
  #pragma unroll
  for (int m = 0; m < 8; m++) acc[m] = make_float4(0.f,0.f,0.f,0.f);

  for (int kb = 0; kb < 4; kb++){
    #pragma unroll
    for (int it = 0; it < 2; it++){
      int i = tid + it*256;
      int r = i >> 3, c4 = i & 7;
      int gr = row0 + r;
      float4 v1 = make_float4(0,0,0,0), v2 = v1;
      if (gr < N){
        v1 = ld4(A1 + (size_t)gr*128 + kb*32 + c4*4);
        v2 = ld4(A2 + (size_t)gr*128 + kb*32 + c4*4);
      }
      *(float4*)&A1s[r][c4*4] = v1;
      *(float4*)&A2s[r][c4*4] = v2;
    }
    #pragma unroll
    for (int it = 0; it < 4; it++){
      int i = tid + it*256;
      int j = i >> 3, c4 = i & 7;
      float4 w1 = ld4(W1 + j*128 + kb*32 + c4*4);
      float4 w2 = ld4(W2 + j*128 + kb*32 + c4*4);
      W1t[c4*4+0][j] = w1.x; W1t[c4*4+1][j] = w1.y;
      W1t[c4*4+2][j] = w1.z; W1t[c4*4+3][j] = w1.w;
      W2t[c4*4+0][j] = w2.x; W2t[c4*4+1][j] = w2.y;
      W2t[c4*4+2][j] = w2.z; W2t[c4*4+3][j] = w2.w;
    }
    __syncthreads();
    #pragma unroll
    for (int kk = 0; kk < 32; kk++){
      float4 w1 = *(const float4*)&W1t[kk][cg*4];
      float4 w2 = *(const float4*)&W2t[kk][cg*4];
      #pragma unroll
      for (int m = 0; m < 8; m++){
        float a1 = A1s[rs + 8*m][kk];
        float a2 = A2s[rs + 8*m][kk];
        acc[m].x = fmaf(a1, w1.x, acc[m].x);
        acc[m].y = fmaf(a1, w1.y, acc[m].y);
        acc[m].z = fmaf(a1, w1.z, acc[m].z);
        acc[m].w = fmaf(a1, w1.w, acc[m].w);
        acc[m].x = fmaf(a2, w2.x, acc[m].x);
        acc[m].y = fmaf(a2, w2.y, acc[m].y);
        acc[m].z = fmaf(a2, w2.z, acc[m].z);
        acc[m].w = fmaf(a2, w2.w, acc[m].w);
      }
    }
    __syncthreads();
  }

  float4 b = ld4(bias + cg*4);
  double ls1 = 0.0, ls2 = 0.0;
  #pragma unroll
  for (int m = 0; m < 8; m++){
    int r = row0 + rs + 8*m;
    if (r < N){
      float4 v;
      v.x = acc[m].x + b.x; v.y = acc[m].y + b.y;
      v.z = acc[m].z + b.z; v.w = acc[m].w + b.w;
      *(float4*)(out + (size_t)r*128 + cg*4) = v;
      ls1 += (double)v.x + (double)v.y + (double)v.z + (double)v.w;
      ls2 += (double)v.x*v.x + (double)v.y*v.y + (double)v.z*v.z + (double)v.w*v.w;
    }
  }
  #pragma unroll
  for (int off = 32; off > 0; off >>= 1){
    ls1 += __shfl_down(ls1, off);
    ls2 += __shfl_down(ls2, off);
  }
  __shared__ double red[8];
  int wid = tid >> 6;
  if ((tid & 63) == 0){ red[wid*2] = ls1; red[wid*2+1] = ls2; }
  __syncthreads();
  if (tid == 0){
    atomicAdd(&stats[0], red[0]+red[2]+red[4]+red[6]);
    atomicAdd(&stats[1], red[1]+red[3]+red[5]+red[7]);
  }
}

// ---------------- skip GEMM: out = A@W^T + prelu(ln0(T0)) ----------------
__global__ __launch_bounds__(256) void gemm_skip_kernel(
    const float* __restrict__ A, const float* __restrict__ W,
    const float* __restrict__ T0, const double* __restrict__ stats,
    const float* __restrict__ lnw, const float* __restrict__ lnb,
    const float* __restrict__ pw,
    float* __restrict__ out, int N, double inv_cnt){
  __shared__ float As[64][32];
  __shared__ float Wt[32][132];

  const int tid = threadIdx.x;
  const int cg  = tid & 31;
  const int rs  = tid >> 5;
  const int row0 = blockIdx.x * 64;

  float4 acc[8];
  #pragma unroll
  for (int m = 0; m < 8; m++) acc[m] = make_float4(0.f,0.f,0.f,0.f);

  for (int kb = 0; kb < 4; kb++){
    #pragma unroll
    for (int it = 0; it < 2; it++){
      int i = tid + it*256;
      int r = i >> 3, c4 = i & 7;
      int gr = row0 + r;
      float4 v = make_float4(0,0,0,0);
      if (gr < N) v = ld4(A + (size_t)gr*128 + kb*32 + c4*4);
      *(float4*)&As[r][c4*4] = v;
    }
    #pragma unroll
    for (int it = 0; it < 4; it++){
      int i = tid + it*256;
      int j = i >> 3, c4 = i & 7;
      float4 w = ld4(W + j*128 + kb*32 + c4*4);
      Wt[c4*4+0][j] = w.x; Wt[c4*4+1][j] = w.y;
      Wt[c4*4+2][j] = w.z; Wt[c4*4+3][j] = w.w;
    }
    __syncthreads();
    #pragma unroll
    for (int kk = 0; kk < 32; kk++){
      float4 w = *(const float4*)&Wt[kk][cg*4];
      #pragma unroll
      for (int m = 0; m < 8; m++){
        float a = As[rs + 8*m][kk];
        acc[m].x = fmaf(a, w.x, acc[m].x);
        acc[m].y = fmaf(a, w.y, acc[m].y);
        acc[m].z = fmaf(a, w.z, acc[m].z);
        acc[m].w = fmaf(a, w.w, acc[m].w);
      }
    }
    __syncthreads();
  }

  double s1 = stats[0], s2 = stats[1];
  double md = s1 * inv_cnt;
  double var = s2 * inv_cnt - md*md;
  float mean = (float)md;
  float rstd = 1.f / ((float)sqrt(fmax(var, 0.0)) + LN_EPS);
  float slope = pw[0];
  float4 w4 = ld4(lnw + cg*4);
  float4 b4 = ld4(lnb + cg*4);

  #pragma unroll
  for (int m = 0; m < 8; m++){
    int r = row0 + rs + 8*m;
    if (r < N){
      float4 t = ld4(T0 + (size_t)r*128 + cg*4);
      float4 v;
      float l;
      l = (t.x - mean)*rstd*w4.x + b4.x; v.x = acc[m].x + (l >= 0.f ? l : slope*l);
      l = (t.y - mean)*rstd*w4.y + b4.y; v.y = acc[m].y + (l >= 0.f ? l : slope*l);
      l = (t.z - mean)*rstd*w4.z + b4.z; v.z = acc[m].z + (l >= 0.f ? l : slope*l);
      l = (t.w - mean)*rstd*w4.w + b4.w; v.w = acc[m].w + (l >= 0.f ? l : slope*l);
      *(float4*)(out + (size_t)r*128 + cg*4) = v;
    }
  }
}

// ---------------- final elementwise: out = prelu(ln1(T)) ----------------
__global__ __launch_bounds__(256) void ln_prelu_kernel(
    const float* __restrict__ T, const double* __restrict__ stats,
    const float* __restrict__ lnw, const float* __restrict__ lnb,
    const float* __restrict__ pw, float* __restrict__ out,
    int nf4, double inv_cnt){
  double s1 = stats[0], s2 = stats[1];
  double md = s1 * inv_cnt;
  double var = s2 * inv_cnt - md*md;
  float mean = (float)md;
  float rstd = 1.f / ((float)sqrt(fmax(var, 0.0)) + LN_EPS);
  float slope = pw[0];
  for (int i = blockIdx.x*256 + threadIdx.x; i < nf4; i += gridDim.x*256){
    int c4 = i & 31;
    float4 t = ld4(T + (size_t)i*4);
    float4 w4 = ld4(lnw + c4*4);
    float4 b4 = ld4(lnb + c4*4);
    float4 v; float l;
    l = (t.x - mean)*rstd*w4.x + b4.x; v.x = (l >= 0.f ? l : slope*l);
    l = (t.y - mean)*rstd*w4.y + b4.y; v.y = (l >= 0.f ? l : slope*l);
    l = (t.z - mean)*rstd*w4.z + b4.z; v.z = (l >= 0.f ? l : slope*l);
    l = (t.w - mean)*rstd*w4.w + b4.w; v.w = (l >= 0.f ? l : slope*l);
    *(float4*)(out + (size_t)i*4) = v;
  }
}

extern "C" void kernel_launch(void* const* d_in, const int* in_sizes, int n_in,
                              void* d_out, int out_size, void* d_ws, size_t ws_size,
                              hipStream_t stream){
  const float* x    = (const float*)d_in[0];
  const int*   ei   = (const int*)d_in[1];
  const float* Wl0  = (const float*)d_in[2];
  const float* bl0  = (const float*)d_in[3];
  const float* Wr0  = (const float*)d_in[4];
  const float* lnw0 = (const float*)d_in[5];
  const float* lnb0 = (const float*)d_in[6];
  const float* pw0  = (const float*)d_in[7];
  const float* skW  = (const float*)d_in[8];
  const float* Wl1  = (const float*)d_in[9];
  const float* bl1  = (const float*)d_in[10];
  const float* Wr1  = (const float*)d_in[11];
  const float* lnw1 = (const float*)d_in[12];
  const float* lnb1 = (const float*)d_in[13];
  const float* pw1  = (const float*)d_in[14];

  const int N = in_sizes[0] / 128;
  const int E = in_sizes[1] / 2;

  char* p = (char*)d_ws;
  auto carve = [&](size_t bytes)->char*{
    char* r = p;
    p += (bytes + 255) & ~(size_t)255;
    return r;
  };
  double* stats   = (double*)carve(4*sizeof(double));
  int*    flag    = (int*)carve(sizeof(int));
  int*    deg     = (int*)carve((size_t)N*4);
  int*    rowst   = (int*)carve((size_t)N*4);
  int*    cursor  = (int*)carve((size_t)N*4);
  int*    srcb    = (int*)carve((size_t)E*4);
  int*    dstb    = (int*)carve((size_t)E*4);
  int*    csr     = (int*)carve((size_t)E*4);
  float*  meanbuf = (float*)carve((size_t)N*128*4);
  float*  tbuf    = (float*)carve((size_t)N*128*4);
  float*  hskip   = (float*)d_out;   // layer-1 input lives in d_out until overwritten

  hipMemsetAsync(stats, 0, 4*sizeof(double), stream);
  hipMemsetAsync(deg, 0, (size_t)N*4, stream);

  int eb = (E + 255)/256;
  detect_fmt_kernel<<<1, 256, 0, stream>>>(ei, flag);
  extract_edges_kernel<<<eb, 256, 0, stream>>>(ei, E, flag, srcb, dstb);
  count_deg_kernel<<<eb, 256, 0, stream>>>(dstb, deg, E);
  scan_kernel<<<1, 1024, 0, stream>>>(deg, rowst, cursor, N);
  scatter_kernel<<<eb, 256, 0, stream>>>(srcb, dstb, cursor, csr, E);

  int ab = (N + 3)/4;
  int gb = (N + 63)/64;
  double inv_cnt = 1.0 / ((double)N * 128.0);

  // layer 0
  aggregate_kernel<<<ab, 256, 0, stream>>>(x, csr, rowst, deg, meanbuf, N);
  gemm_dual_kernel<<<gb, 256, 0, stream>>>(meanbuf, x, Wl0, Wr0, bl0, tbuf, N, stats);
  gemm_skip_kernel<<<gb, 256, 0, stream>>>(x, skW, tbuf, stats, lnw0, lnb0, pw0, hskip, N, inv_cnt);
  // layer 1
  aggregate_kernel<<<ab, 256, 0, stream>>>(hskip, csr, rowst, deg, meanbuf, N);
  gemm_dual_kernel<<<gb, 256, 0, stream>>>(meanbuf, hskip, Wl1, Wr1, bl1, tbuf, N, stats + 2);
  ln_prelu_kernel<<<2048, 256, 0, stream>>>(tbuf, stats + 2, lnw1, lnb1, pw1, (float*)d_out, N*32, inv_cnt);
}

// Round 2
// 482.065 us; speedup vs baseline: 1.2144x; 1.2144x over previous
//
#include <hip/hip_runtime.h>

#define LN_EPS 1e-5f

static __device__ __forceinline__ float4 ld4(const float* p){ return *(const float4*)p; }

// ---------------- edge format detect + extract ----------------
// flag=1 -> int32 layout; flag=0 -> int64 little-endian layout
__global__ void detect_fmt_kernel(const int* __restrict__ ei, int* __restrict__ flag){
  __shared__ int any;
  if (threadIdx.x == 0) any = 0;
  __syncthreads();
  int nz = 0;
  for (int i = threadIdx.x; i < 1024; i += 256)
    nz |= (ei[2*i+1] != 0);
  if (nz) atomicOr(&any, 1);
  __syncthreads();
  if (threadIdx.x == 0) *flag = any;
}

// extract src/dst AND count in-degree in one pass
__global__ void extract_edges_kernel(const int* __restrict__ ei, int E,
                                     const int* __restrict__ flag,
                                     int* __restrict__ src, int* __restrict__ dst,
                                     int* __restrict__ deg){
  int e = blockIdx.x*256 + threadIdx.x;
  if (e >= E) return;
  int s, d;
  if (*flag){           // int32 [2][E]
    s = ei[e];
    d = ei[E + e];
  } else {              // int64 [2][E], values < 2^31 so low word suffices
    s = ei[2*e];
    d = ei[2*(E + e)];
  }
  src[e] = s;
  dst[e] = d;
  atomicAdd(&deg[d], 1);
}

// ---------------- multi-block exclusive scan of deg -> row_start/cursor ----------------
// pass 1: per-block (4096 elems) sums
__global__ __launch_bounds__(256) void scan_part_kernel(const int* __restrict__ deg,
    int* __restrict__ bsum, int n){
  int t = threadIdx.x;
  int base = blockIdx.x*4096 + t*16;
  int s = 0;
  if (base + 16 <= n){
    #pragma unroll
    for (int j = 0; j < 4; j++){
      int4 v = *(const int4*)(deg + base + j*4);
      s += v.x + v.y + v.z + v.w;
    }
  } else {
    for (int j = 0; j < 16; j++) if (base + j < n) s += deg[base+j];
  }
  #pragma unroll
  for (int off = 32; off > 0; off >>= 1) s += __shfl_down(s, off);
  __shared__ int ws[4];
  if ((t & 63) == 0) ws[t>>6] = s;
  __syncthreads();
  if (t == 0) bsum[blockIdx.x] = ws[0]+ws[1]+ws[2]+ws[3];
}

// pass 2: exclusive scan of block sums (nb <= 64)
__global__ void scan_top_kernel(const int* __restrict__ bsum, int* __restrict__ boff, int nb){
  int t = threadIdx.x;   // 64 threads
  int own = (t < nb) ? bsum[t] : 0;
  int v = own;
  #pragma unroll
  for (int off = 1; off < 64; off <<= 1){
    int u = __shfl_up(v, off);
    if (t >= off) v += u;
  }
  if (t < nb) boff[t] = v - own;
}

// pass 3: per-element exclusive prefix, write row_start + cursor
__global__ __launch_bounds__(256) void scan_out_kernel(const int* __restrict__ deg,
    const int* __restrict__ boff, int* __restrict__ row_start,
    int* __restrict__ cursor, int n){
  int t = threadIdx.x;
  int base = blockIdx.x*4096 + t*16;
  int vals[16];
  int s = 0;
  #pragma unroll
  for (int j = 0; j < 16; j++){
    int idx = base + j;
    int d = (idx < n) ? deg[idx] : 0;
    vals[j] = d; s += d;
  }
  int own = s;
  int lane = t & 63;
  #pragma unroll
  for (int off = 1; off < 64; off <<= 1){
    int u = __shfl_up(s, off);
    if (lane >= off) s += u;
  }
  __shared__ int ws[4];
  int w = t >> 6;
  if (lane == 63) ws[w] = s;
  __syncthreads();
  int woff = 0;
  for (int i = 0; i < w; i++) woff += ws[i];
  int run = boff[blockIdx.x] + woff + (s - own);
  #pragma unroll
  for (int j = 0; j < 16; j++){
    int idx = base + j;
    if (idx < n){ row_start[idx] = run; cursor[idx] = run; }
    run += vals[j];
  }
}

__global__ void scatter_kernel(const int* __restrict__ src, const int* __restrict__ dst,
                               int* __restrict__ cursor, int* __restrict__ csr, int E){
  int e = blockIdx.x*256 + threadIdx.x;
  if (e >= E) return;
  int d = dst[e];
  int p = atomicAdd(&cursor[d], 1);
  csr[p] = src[e];
}

// ---------------- segmented mean (1 wave per node) ----------------
__global__ __launch_bounds__(256) void aggregate_kernel(const float* __restrict__ h,
    const int* __restrict__ csr, const int* __restrict__ row_start,
    const int* __restrict__ deg, float* __restrict__ outmean, int N){
  int node = blockIdx.x*4 + (threadIdx.x >> 6);
  if (node >= N) return;
  int lane = threadIdx.x & 63;
  int start = row_start[node];
  int d = deg[node];
  float ax = 0.f, ay = 0.f;
  int e = 0;
  for (; e + 4 <= d; e += 4){
    int j0 = csr[start+e+0], j1 = csr[start+e+1];
    int j2 = csr[start+e+2], j3 = csr[start+e+3];
    float2 v0 = *(const float2*)(h + (size_t)j0*128 + lane*2);
    float2 v1 = *(const float2*)(h + (size_t)j1*128 + lane*2);
    float2 v2 = *(const float2*)(h + (size_t)j2*128 + lane*2);
    float2 v3 = *(const float2*)(h + (size_t)j3*128 + lane*2);
    ax += v0.x + v1.x + v2.x + v3.x;
    ay += v0.y + v1.y + v2.y + v3.y;
  }
  for (; e < d; e++){
    int j = csr[start+e];
    float2 v = *(const float2*)(h + (size_t)j*128 + lane*2);
    ax += v.x; ay += v.y;
  }
  float inv = 1.f / fmaxf((float)d, 1.f);
  float2 r; r.x = ax*inv; r.y = ay*inv;
  *(float2*)(outmean + (size_t)node*128 + lane*2) = r;
}

// ---------------- dual GEMM: out = A1@W1^T + A2@W2^T + bias, + LN stats ----------------
__global__ __launch_bounds__(256) void gemm_dual_kernel(
    const float* __restrict__ A1, const float* __restrict__ A2,
    const float* __restrict__ W1, const float* __restrict__ W2,
    const float* __restrict__ bias,
    float* __restrict__ out, int N, double* __restrict__ stats){
  __shared__ float A1s[64][32];
  __shared__ float A2s[64][32];
  __shared__ float W1t[32][132];
  __shared__ float W2t[32][132];

  const int tid = threadIdx.x;
  const int cg  = tid & 31;      // cols 4cg..4cg+3
  const int rs  = tid >> 5;      // 0..7, rows rs+8m
  const int row0 = blockIdx.x * 64;

  float4 acc[8];
  #pragma unroll
  for (int m = 0; m < 8; m++) acc[m] = make_float4(0.f,0.f,0.f,0.f);

  for (int kb = 0; kb < 4; kb++){
    #pragma unroll
    for (int it = 0; it < 2; it++){
      int i = tid + it*256;
      int r = i >> 3, c4 = i & 7;
      int gr = row0 + r;
      float4 v1 = make_float4(0,0,0,0), v2 = v1;
      if (gr < N){
        v1 = ld4(A1 + (size_t)gr*128 + kb*32 + c4*4);
        v2 = ld4(A2 + (size_t)gr*128 + kb*32 + c4*4);
      }
      *(float4*)&A1s[r][c4*4] = v1;
      *(float4*)&A2s[r][c4*4] = v2;
    }
    #pragma unroll
    for (int it = 0; it < 4; it++){
      int i = tid + it*256;
      int j = i >> 3, c4 = i & 7;
      float4 w1 = ld4(W1 + j*128 + kb*32 + c4*4);
      float4 w2 = ld4(W2 + j*128 + kb*32 + c4*4);
      W1t[c4*4+0][j] = w1.x; W1t[c4*4+1][j] = w1.y;
      W1t[c4*4+2][j] = w1.z; W1t[c4*4+3][j] = w1.w;
      W2t[c4*4+0][j] = w2.x; W2t[c4*4+1][j] = w2.y;
      W2t[c4*4+2][j] = w2.z; W2t[c4*4+3][j] = w2.w;
    }
    __syncthreads();
    #pragma unroll
    for (int kk = 0; kk < 32; kk++){
      float4 w1 = *(const float4*)&W1t[kk][cg*4];
      float4 w2 = *(const float4*)&W2t[kk][cg*4];
      #pragma unroll
      for (int m = 0; m < 8; m++){
        float a1 = A1s[rs + 8*m][kk];
        float a2 = A2s[rs + 8*m][kk];
        acc[m].x = fmaf(a1, w1.x, acc[m].x);
        acc[m].y = fmaf(a1, w1.y, acc[m].y);
        acc[m].z = fmaf(a1, w1.z, acc[m].z);
        acc[m].w = fmaf(a1, w1.w, acc[m].w);
        acc[m].x = fmaf(a2, w2.x, acc[m].x);
        acc[m].y = fmaf(a2, w2.y, acc[m].y);
        acc[m].z = fmaf(a2, w2.z, acc[m].z);
        acc[m].w = fmaf(a2, w2.w, acc[m].w);
      }
    }
    __syncthreads();
  }

  float4 b = ld4(bias + cg*4);
  double ls1 = 0.0, ls2 = 0.0;
  #pragma unroll
  for (int m = 0; m < 8; m++){
    int r = row0 + rs + 8*m;
    if (r < N){
      float4 v;
      v.x = acc[m].x + b.x; v.y = acc[m].y + b.y;
      v.z = acc[m].z + b.z; v.w = acc[m].w + b.w;
      *(float4*)(out + (size_t)r*128 + cg*4) = v;
      ls1 += (double)v.x + (double)v.y + (double)v.z + (double)v.w;
      ls2 += (double)v.x*v.x + (double)v.y*v.y + (double)v.z*v.z + (double)v.w*v.w;
    }
  }
  #pragma unroll
  for (int off = 32; off > 0; off >>= 1){
    ls1 += __shfl_down(ls1, off);
    ls2 += __shfl_down(ls2, off);
  }
  __shared__ double red[8];
  int wid = tid >> 6;
  if ((tid & 63) == 0){ red[wid*2] = ls1; red[wid*2+1] = ls2; }
  __syncthreads();
  if (tid == 0){
    atomicAdd(&stats[0], red[0]+red[2]+red[4]+red[6]);
    atomicAdd(&stats[1], red[1]+red[3]+red[5]+red[7]);
  }
}

// ---------------- skip GEMM: out = A@W^T + prelu(ln0(T0)) ----------------
__global__ __launch_bounds__(256) void gemm_skip_kernel(
    const float* __restrict__ A, const float* __restrict__ W,
    const float* __restrict__ T0, const double* __restrict__ stats,
    const float* __restrict__ lnw, const float* __restrict__ lnb,
    const float* __restrict__ pw,
    float* __restrict__ out, int N, double inv_cnt){
  __shared__ float As[64][32];
  __shared__ float Wt[32][132];

  const int tid = threadIdx.x;
  const int cg  = tid & 31;
  const int rs  = tid >> 5;
  const int row0 = blockIdx.x * 64;

  float4 acc[8];
  #pragma unroll
  for (int m = 0; m < 8; m++) acc[m] = make_float4(0.f,0.f,0.f,0.f);

  for (int kb = 0; kb < 4; kb++){
    #pragma unroll
    for (int it = 0; it < 2; it++){
      int i = tid + it*256;
      int r = i >> 3, c4 = i & 7;
      int gr = row0 + r;
      float4 v = make_float4(0,0,0,0);
      if (gr < N) v = ld4(A + (size_t)gr*128 + kb*32 + c4*4);
      *(float4*)&As[r][c4*4] = v;
    }
    #pragma unroll
    for (int it = 0; it < 4; it++){
      int i = tid + it*256;
      int j = i >> 3, c4 = i & 7;
      float4 w = ld4(W + j*128 + kb*32 + c4*4);
      Wt[c4*4+0][j] = w.x; Wt[c4*4+1][j] = w.y;
      Wt[c4*4+2][j] = w.z; Wt[c4*4+3][j] = w.w;
    }
    __syncthreads();
    #pragma unroll
    for (int kk = 0; kk < 32; kk++){
      float4 w = *(const float4*)&Wt[kk][cg*4];
      #pragma unroll
      for (int m = 0; m < 8; m++){
        float a = As[rs + 8*m][kk];
        acc[m].x = fmaf(a, w.x, acc[m].x);
        acc[m].y = fmaf(a, w.y, acc[m].y);
        acc[m].z = fmaf(a, w.z, acc[m].z);
        acc[m].w = fmaf(a, w.w, acc[m].w);
      }
    }
    __syncthreads();
  }

  double s1 = stats[0], s2 = stats[1];
  double md = s1 * inv_cnt;
  double var = s2 * inv_cnt - md*md;
  float mean = (float)md;
  float rstd = 1.f / ((float)sqrt(fmax(var, 0.0)) + LN_EPS);
  float slope = pw[0];
  float4 w4 = ld4(lnw + cg*4);
  float4 b4 = ld4(lnb + cg*4);

  #pragma unroll
  for (int m = 0; m < 8; m++){
    int r = row0 + rs + 8*m;
    if (r < N){
      float4 t = ld4(T0 + (size_t)r*128 + cg*4);
      float4 v;
      float l;
      l = (t.x - mean)*rstd*w4.x + b4.x; v.x = acc[m].x + (l >= 0.f ? l : slope*l);
      l = (t.y - mean)*rstd*w4.y + b4.y; v.y = acc[m].y + (l >= 0.f ? l : slope*l);
      l = (t.z - mean)*rstd*w4.z + b4.z; v.z = acc[m].z + (l >= 0.f ? l : slope*l);
      l = (t.w - mean)*rstd*w4.w + b4.w; v.w = acc[m].w + (l >= 0.f ? l : slope*l);
      *(float4*)(out + (size_t)r*128 + cg*4) = v;
    }
  }
}

// ---------------- final elementwise: out = prelu(ln1(T)) ----------------
__global__ __launch_bounds__(256) void ln_prelu_kernel(
    const float* __restrict__ T, const double* __restrict__ stats,
    const float* __restrict__ lnw, const float* __restrict__ lnb,
    const float* __restrict__ pw, float* __restrict__ out,
    int nf4, double inv_cnt){
  double s1 = stats[0], s2 = stats[1];
  double md = s1 * inv_cnt;
  double var = s2 * inv_cnt - md*md;
  float mean = (float)md;
  float rstd = 1.f / ((float)sqrt(fmax(var, 0.0)) + LN_EPS);
  float slope = pw[0];
  for (int i = blockIdx.x*256 + threadIdx.x; i < nf4; i += gridDim.x*256){
    int c4 = i & 31;
    float4 t = ld4(T + (size_t)i*4);
    float4 w4 = ld4(lnw + c4*4);
    float4 b4 = ld4(lnb + c4*4);
    float4 v; float l;
    l = (t.x - mean)*rstd*w4.x + b4.x; v.x = (l >= 0.f ? l : slope*l);
    l = (t.y - mean)*rstd*w4.y + b4.y; v.y = (l >= 0.f ? l : slope*l);
    l = (t.z - mean)*rstd*w4.z + b4.z; v.z = (l >= 0.f ? l : slope*l);
    l = (t.w - mean)*rstd*w4.w + b4.w; v.w = (l >= 0.f ? l : slope*l);
    *(float4*)(out + (size_t)i*4) = v;
  }
}

extern "C" void kernel_launch(void* const* d_in, const int* in_sizes, int n_in,
                              void* d_out, int out_size, void* d_ws, size_t ws_size,
                              hipStream_t stream){
  const float* x    = (const float*)d_in[0];
  const int*   ei   = (const int*)d_in[1];
  const float* Wl0  = (const float*)d_in[2];
  const float* bl0  = (const float*)d_in[3];
  const float* Wr0  = (const float*)d_in[4];
  const float* lnw0 = (const float*)d_in[5];
  const float* lnb0 = (const float*)d_in[6];
  const float* pw0  = (const float*)d_in[7];
  const float* skW  = (const float*)d_in[8];
  const float* Wl1  = (const float*)d_in[9];
  const float* bl1  = (const float*)d_in[10];
  const float* Wr1  = (const float*)d_in[11];
  const float* lnw1 = (const float*)d_in[12];
  const float* lnb1 = (const float*)d_in[13];
  const float* pw1  = (const float*)d_in[14];

  const int N = in_sizes[0] / 128;
  const int E = in_sizes[1] / 2;

  char* p = (char*)d_ws;
  auto carve = [&](size_t bytes)->char*{
    char* r = p;
    p += (bytes + 255) & ~(size_t)255;
    return r;
  };
  double* stats   = (double*)carve(4*sizeof(double));
  int*    flag    = (int*)carve(sizeof(int));
  int*    bsum    = (int*)carve(64*4);
  int*    boff    = (int*)carve(64*4);
  int*    deg     = (int*)carve((size_t)N*4);
  int*    rowst   = (int*)carve((size_t)N*4);
  int*    cursor  = (int*)carve((size_t)N*4);
  int*    srcb    = (int*)carve((size_t)E*4);
  int*    dstb    = (int*)carve((size_t)E*4);
  int*    csr     = (int*)carve((size_t)E*4);
  float*  meanbuf = (float*)carve((size_t)N*128*4);
  float*  tbuf    = (float*)carve((size_t)N*128*4);
  float*  hskip   = (float*)d_out;   // layer-1 input lives in d_out until overwritten

  hipMemsetAsync(stats, 0, 4*sizeof(double), stream);
  hipMemsetAsync(deg, 0, (size_t)N*4, stream);

  int eb = (E + 255)/256;
  int nb = (N + 4095)/4096;   // blocks for scan (<= 64)
  detect_fmt_kernel<<<1, 256, 0, stream>>>(ei, flag);
  extract_edges_kernel<<<eb, 256, 0, stream>>>(ei, E, flag, srcb, dstb, deg);
  scan_part_kernel<<<nb, 256, 0, stream>>>(deg, bsum, N);
  scan_top_kernel<<<1, 64, 0, stream>>>(bsum, boff, nb);
  scan_out_kernel<<<nb, 256, 0, stream>>>(deg, boff, rowst, cursor, N);
  scatter_kernel<<<eb, 256, 0, stream>>>(srcb, dstb, cursor, csr, E);

  int ab = (N + 3)/4;
  int gb = (N + 63)/64;
  double inv_cnt = 1.0 / ((double)N * 128.0);

  // layer 0
  aggregate_kernel<<<ab, 256, 0, stream>>>(x, csr, rowst, deg, meanbuf, N);
  gemm_dual_kernel<<<gb, 256, 0, stream>>>(meanbuf, x, Wl0, Wr0, bl0, tbuf, N, stats);
  gemm_skip_kernel<<<gb, 256, 0, stream>>>(x, skW, tbuf, stats, lnw0, lnb0, pw0, hskip, N, inv_cnt);
  // layer 1
  aggregate_kernel<<<ab, 256, 0, stream>>>(hskip, csr, rowst, deg, meanbuf, N);
  gemm_dual_kernel<<<gb, 256, 0, stream>>>(meanbuf, hskip, Wl1, Wr1, bl1, tbuf, N, stats + 2);
  ln_prelu_kernel<<<2048, 256, 0, stream>>>(tbuf, stats + 2, lnw1, lnb1, pw1, (float*)d_out, N*32, inv_cnt);
}

// Round 3
// 360.175 us; speedup vs baseline: 1.6254x; 1.3384x over previous
//
#include <hip/hip_runtime.h>

#define LN_EPS 1e-5f

typedef short bf16x8 __attribute__((ext_vector_type(8)));
typedef float f32x4  __attribute__((ext_vector_type(4)));

static __device__ __forceinline__ float4 ld4(const float* p){ return *(const float4*)p; }
static __device__ __forceinline__ uint f2bf1(float f){
  uint u = __float_as_uint(f);
  return (u + 0x7fffu + ((u >> 16) & 1u)) >> 16;     // RNE
}
static __device__ __forceinline__ float bf2f(uint lo16){ return __uint_as_float(lo16 << 16); }

// ---------------- edge format detect + extract (+degree) ----------------
__global__ void detect_fmt_kernel(const int* __restrict__ ei, int* __restrict__ flag){
  __shared__ int any;
  if (threadIdx.x == 0) any = 0;
  __syncthreads();
  int nz = 0;
  for (int i = threadIdx.x; i < 1024; i += 256)
    nz |= (ei[2*i+1] != 0);
  if (nz) atomicOr(&any, 1);
  __syncthreads();
  if (threadIdx.x == 0) *flag = any;
}

__global__ void extract_edges_kernel(const int* __restrict__ ei, int E,
                                     const int* __restrict__ flag,
                                     int* __restrict__ src, int* __restrict__ dst,
                                     int* __restrict__ deg){
  int e = blockIdx.x*256 + threadIdx.x;
  if (e >= E) return;
  int s, d;
  if (*flag){           // int32 [2][E]
    s = ei[e];
    d = ei[E + e];
  } else {              // int64 [2][E] little-endian, values < 2^31
    s = ei[2*e];
    d = ei[2*(E + e)];
  }
  src[e] = s;
  dst[e] = d;
  atomicAdd(&deg[d], 1);
}

// ---------------- bf16 conversion ----------------
__global__ void convert_bf16_kernel(const float* __restrict__ src, ushort* __restrict__ dst, int n8){
  int i = blockIdx.x*256 + threadIdx.x;
  if (i >= n8) return;
  float4 a = ld4(src + (size_t)i*8);
  float4 b = ld4(src + (size_t)i*8 + 4);
  uint4 o;
  o.x = f2bf1(a.x) | (f2bf1(a.y) << 16);
  o.y = f2bf1(a.z) | (f2bf1(a.w) << 16);
  o.z = f2bf1(b.x) | (f2bf1(b.y) << 16);
  o.w = f2bf1(b.z) | (f2bf1(b.w) << 16);
  *(uint4*)(dst + (size_t)i*8) = o;
}

__global__ void convert_w_kernel(const float* __restrict__ s0, const float* __restrict__ s1,
                                 const float* __restrict__ s2, const float* __restrict__ s3,
                                 const float* __restrict__ s4, ushort* __restrict__ dst){
  int i = blockIdx.x*256 + threadIdx.x;     // 10240 threads, 8 elems each
  if (i >= 10240) return;
  int m = i >> 11;
  int o = (i & 2047) * 8;
  const float* s = (m == 0) ? s0 : (m == 1) ? s1 : (m == 2) ? s2 : (m == 3) ? s3 : s4;
  float4 a = ld4(s + o);
  float4 b = ld4(s + o + 4);
  uint4 v;
  v.x = f2bf1(a.x) | (f2bf1(a.y) << 16);
  v.y = f2bf1(a.z) | (f2bf1(a.w) << 16);
  v.z = f2bf1(b.x) | (f2bf1(b.y) << 16);
  v.w = f2bf1(b.z) | (f2bf1(b.w) << 16);
  *(uint4*)(dst + (size_t)m*16384 + o) = v;
}

// ---------------- multi-block exclusive scan of deg ----------------
__global__ __launch_bounds__(256) void scan_part_kernel(const int* __restrict__ deg,
    int* __restrict__ bsum, int n){
  int t = threadIdx.x;
  int base = blockIdx.x*4096 + t*16;
  int s = 0;
  if (base + 16 <= n){
    #pragma unroll
    for (int j = 0; j < 4; j++){
      int4 v = *(const int4*)(deg + base + j*4);
      s += v.x + v.y + v.z + v.w;
    }
  } else {
    for (int j = 0; j < 16; j++) if (base + j < n) s += deg[base+j];
  }
  #pragma unroll
  for (int off = 32; off > 0; off >>= 1) s += __shfl_down(s, off);
  __shared__ int ws[4];
  if ((t & 63) == 0) ws[t>>6] = s;
  __syncthreads();
  if (t == 0) bsum[blockIdx.x] = ws[0]+ws[1]+ws[2]+ws[3];
}

__global__ void scan_top_kernel(const int* __restrict__ bsum, int* __restrict__ boff, int nb){
  int t = threadIdx.x;   // 64 threads
  int own = (t < nb) ? bsum[t] : 0;
  int v = own;
  #pragma unroll
  for (int off = 1; off < 64; off <<= 1){
    int u = __shfl_up(v, off);
    if (t >= off) v += u;
  }
  if (t < nb) boff[t] = v - own;
}

__global__ __launch_bounds__(256) void scan_out_kernel(const int* __restrict__ deg,
    const int* __restrict__ boff, int* __restrict__ row_start,
    int* __restrict__ cursor, int n){
  int t = threadIdx.x;
  int base = blockIdx.x*4096 + t*16;
  int vals[16];
  int s = 0;
  #pragma unroll
  for (int j = 0; j < 16; j++){
    int idx = base + j;
    int d = (idx < n) ? deg[idx] : 0;
    vals[j] = d; s += d;
  }
  int own = s;
  int lane = t & 63;
  #pragma unroll
  for (int off = 1; off < 64; off <<= 1){
    int u = __shfl_up(s, off);
    if (lane >= off) s += u;
  }
  __shared__ int ws[4];
  int w = t >> 6;
  if (lane == 63) ws[w] = s;
  __syncthreads();
  int woff = 0;
  for (int i = 0; i < w; i++) woff += ws[i];
  int run = boff[blockIdx.x] + woff + (s - own);
  #pragma unroll
  for (int j = 0; j < 16; j++){
    int idx = base + j;
    if (idx < n){ row_start[idx] = run; cursor[idx] = run; }
    run += vals[j];
  }
}

__global__ void scatter_kernel(const int* __restrict__ src, const int* __restrict__ dst,
                               int* __restrict__ cursor, int* __restrict__ csr, int E){
  int e = blockIdx.x*256 + threadIdx.x;
  if (e >= E) return;
  int d = dst[e];
  int p = atomicAdd(&cursor[d], 1);
  csr[p] = src[e];
}

// ---------------- segmented mean over bf16 rows (1 wave per node) ----------------
__global__ __launch_bounds__(256) void aggregate_kernel(const ushort* __restrict__ h,
    const int* __restrict__ csr, const int* __restrict__ row_start,
    const int* __restrict__ deg, ushort* __restrict__ outmean, int N){
  int node = blockIdx.x*4 + (threadIdx.x >> 6);
  if (node >= N) return;
  int lane = threadIdx.x & 63;
  const uint* hp = (const uint*)h;     // [N][64] packed pairs
  uint* op = (uint*)outmean;
  int start = row_start[node];
  int d = deg[node];
  float ax = 0.f, ay = 0.f;
  int e = 0;
  for (; e + 4 <= d; e += 4){
    int j0 = csr[start+e+0], j1 = csr[start+e+1];
    int j2 = csr[start+e+2], j3 = csr[start+e+3];
    uint v0 = hp[(size_t)j0*64 + lane];
    uint v1 = hp[(size_t)j1*64 + lane];
    uint v2 = hp[(size_t)j2*64 + lane];
    uint v3 = hp[(size_t)j3*64 + lane];
    ax += bf2f(v0 & 0xffffu) + bf2f(v1 & 0xffffu) + bf2f(v2 & 0xffffu) + bf2f(v3 & 0xffffu);
    ay += bf2f(v0 >> 16) + bf2f(v1 >> 16) + bf2f(v2 >> 16) + bf2f(v3 >> 16);
  }
  for (; e < d; e++){
    int j = csr[start+e];
    uint v = hp[(size_t)j*64 + lane];
    ax += bf2f(v & 0xffffu);
    ay += bf2f(v >> 16);
  }
  float inv = 1.f / fmaxf((float)d, 1.f);
  op[(size_t)node*64 + lane] = f2bf1(ax*inv) | (f2bf1(ay*inv) << 16);
}

// ---------------- dual MFMA GEMM: out = A1@W1^T + A2@W2^T + b, + LN stats ----------------
// block = 256 thr / 4 waves, tile 128 rows x 128 cols, wave = 32 rows
__global__ __launch_bounds__(256) void gemm_dual_mfma(
    const ushort* __restrict__ A1, const ushort* __restrict__ A2,
    const ushort* __restrict__ W1, const ushort* __restrict__ W2,
    const float* __restrict__ bias, float* __restrict__ out,
    int N, double* __restrict__ stats){
  const int tid  = threadIdx.x;
  const int lane = tid & 63;
  const int wv   = tid >> 6;
  const int r0   = blockIdx.x*128 + wv*32;
  const int lrow = lane & 15;
  const int lk   = (lane >> 4) * 8;

  f32x4 acc[2][8] = {};

  #pragma unroll
  for (int ks = 0; ks < 4; ks++){
    const int kb = ks*32 + lk;
    bf16x8 a1[2], a2[2];
    #pragma unroll
    for (int m = 0; m < 2; m++){
      int r = r0 + m*16 + lrow;
      if (r > N-1) r = N-1;
      a1[m] = *(const bf16x8*)(A1 + (size_t)r*128 + kb);
      a2[m] = *(const bf16x8*)(A2 + (size_t)r*128 + kb);
    }
    #pragma unroll
    for (int n = 0; n < 8; n++){
      const int c = n*16 + lrow;
      bf16x8 b1 = *(const bf16x8*)(W1 + c*128 + kb);
      bf16x8 b2 = *(const bf16x8*)(W2 + c*128 + kb);
      #pragma unroll
      for (int m = 0; m < 2; m++){
        acc[m][n] = __builtin_amdgcn_mfma_f32_16x16x32_bf16(a1[m], b1, acc[m][n], 0, 0, 0);
        acc[m][n] = __builtin_amdgcn_mfma_f32_16x16x32_bf16(a2[m], b2, acc[m][n], 0, 0, 0);
      }
    }
  }

  float bn[8];
  #pragma unroll
  for (int n = 0; n < 8; n++) bn[n] = bias[n*16 + lrow];

  double ls1 = 0.0, ls2 = 0.0;
  const int rb = (lane >> 4) * 4;
  #pragma unroll
  for (int m = 0; m < 2; m++){
    #pragma unroll
    for (int j = 0; j < 4; j++){
      int r = r0 + m*16 + rb + j;
      if (r < N){
        #pragma unroll
        for (int n = 0; n < 8; n++){
          float v = acc[m][n][j] + bn[n];
          out[(size_t)r*128 + n*16 + lrow] = v;
          ls1 += (double)v;
          ls2 += (double)v * (double)v;
        }
      }
    }
  }
  #pragma unroll
  for (int off = 32; off > 0; off >>= 1){
    ls1 += __shfl_down(ls1, off);
    ls2 += __shfl_down(ls2, off);
  }
  __shared__ double red[8];
  if (lane == 0){ red[wv*2] = ls1; red[wv*2+1] = ls2; }
  __syncthreads();
  if (tid == 0) atomicAdd(&stats[0], red[0]+red[2]+red[4]+red[6]);
  if (tid == 1) atomicAdd(&stats[1], red[1]+red[3]+red[5]+red[7]);
}

// ---------------- skip MFMA GEMM: hskip16 = bf16( A@W^T + prelu(ln0(T0)) ) ----------------
__global__ __launch_bounds__(256) void gemm_skip_mfma(
    const ushort* __restrict__ A, const ushort* __restrict__ W,
    const float* __restrict__ T0, const double* __restrict__ stats,
    const float* __restrict__ lnw, const float* __restrict__ lnb,
    const float* __restrict__ pw,
    ushort* __restrict__ outb, int N, double inv_cnt){
  const int tid  = threadIdx.x;
  const int lane = tid & 63;
  const int wv   = tid >> 6;
  const int r0   = blockIdx.x*128 + wv*32;
  const int lrow = lane & 15;
  const int lk   = (lane >> 4) * 8;

  f32x4 acc[2][8] = {};

  #pragma unroll
  for (int ks = 0; ks < 4; ks++){
    const int kb = ks*32 + lk;
    bf16x8 a[2];
    #pragma unroll
    for (int m = 0; m < 2; m++){
      int r = r0 + m*16 + lrow;
      if (r > N-1) r = N-1;
      a[m] = *(const bf16x8*)(A + (size_t)r*128 + kb);
    }
    #pragma unroll
    for (int n = 0; n < 8; n++){
      const int c = n*16 + lrow;
      bf16x8 b = *(const bf16x8*)(W + c*128 + kb);
      #pragma unroll
      for (int m = 0; m < 2; m++)
        acc[m][n] = __builtin_amdgcn_mfma_f32_16x16x32_bf16(a[m], b, acc[m][n], 0, 0, 0);
    }
  }

  double s1 = stats[0], s2 = stats[1];
  double md = s1 * inv_cnt;
  double var = s2 * inv_cnt - md*md;
  float mean = (float)md;
  float rstd = 1.f / ((float)sqrt(fmax(var, 0.0)) + LN_EPS);
  float slope = pw[0];
  float wn[8], bb[8];
  #pragma unroll
  for (int n = 0; n < 8; n++){
    wn[n] = lnw[n*16 + lrow];
    bb[n] = lnb[n*16 + lrow];
  }

  const int rb = (lane >> 4) * 4;
  #pragma unroll
  for (int m = 0; m < 2; m++){
    #pragma unroll
    for (int j = 0; j < 4; j++){
      int r = r0 + m*16 + rb + j;
      if (r < N){
        #pragma unroll
        for (int n = 0; n < 8; n++){
          float t = T0[(size_t)r*128 + n*16 + lrow];
          float l = (t - mean)*rstd*wn[n] + bb[n];
          l = (l >= 0.f) ? l : slope*l;
          float v = acc[m][n][j] + l;
          outb[(size_t)r*128 + n*16 + lrow] = (ushort)f2bf1(v);
        }
      }
    }
  }
}

// ---------------- final elementwise: out = prelu(ln1(T)) (in-place OK) ----------------
__global__ __launch_bounds__(256) void ln_prelu_kernel(
    const float* __restrict__ T, const double* __restrict__ stats,
    const float* __restrict__ lnw, const float* __restrict__ lnb,
    const float* __restrict__ pw, float* __restrict__ out,
    int nf4, double inv_cnt){
  double s1 = stats[0], s2 = stats[1];
  double md = s1 * inv_cnt;
  double var = s2 * inv_cnt - md*md;
  float mean = (float)md;
  float rstd = 1.f / ((float)sqrt(fmax(var, 0.0)) + LN_EPS);
  float slope = pw[0];
  for (int i = blockIdx.x*256 + threadIdx.x; i < nf4; i += gridDim.x*256){
    int c4 = i & 31;
    float4 t = ld4(T + (size_t)i*4);
    float4 w4 = ld4(lnw + c4*4);
    float4 b4 = ld4(lnb + c4*4);
    float4 v; float l;
    l = (t.x - mean)*rstd*w4.x + b4.x; v.x = (l >= 0.f ? l : slope*l);
    l = (t.y - mean)*rstd*w4.y + b4.y; v.y = (l >= 0.f ? l : slope*l);
    l = (t.z - mean)*rstd*w4.z + b4.z; v.z = (l >= 0.f ? l : slope*l);
    l = (t.w - mean)*rstd*w4.w + b4.w; v.w = (l >= 0.f ? l : slope*l);
    *(float4*)(out + (size_t)i*4) = v;
  }
}

extern "C" void kernel_launch(void* const* d_in, const int* in_sizes, int n_in,
                              void* d_out, int out_size, void* d_ws, size_t ws_size,
                              hipStream_t stream){
  const float* x    = (const float*)d_in[0];
  const int*   ei   = (const int*)d_in[1];
  const float* Wl0  = (const float*)d_in[2];
  const float* bl0  = (const float*)d_in[3];
  const float* Wr0  = (const float*)d_in[4];
  const float* lnw0 = (const float*)d_in[5];
  const float* lnb0 = (const float*)d_in[6];
  const float* pw0  = (const float*)d_in[7];
  const float* skW  = (const float*)d_in[8];
  const float* Wl1  = (const float*)d_in[9];
  const float* bl1  = (const float*)d_in[10];
  const float* Wr1  = (const float*)d_in[11];
  const float* lnw1 = (const float*)d_in[12];
  const float* lnb1 = (const float*)d_in[13];
  const float* pw1  = (const float*)d_in[14];

  const int N = in_sizes[0] / 128;
  const int E = in_sizes[1] / 2;

  char* p = (char*)d_ws;
  auto carve = [&](size_t bytes)->char*{
    char* r = p;
    p += (bytes + 255) & ~(size_t)255;
    return r;
  };
  double* stats   = (double*)carve(4*sizeof(double));
  int*    flag    = (int*)carve(sizeof(int));
  int*    bsum    = (int*)carve(64*4);
  int*    boff    = (int*)carve(64*4);
  int*    deg     = (int*)carve((size_t)N*4);
  int*    rowst   = (int*)carve((size_t)N*4);
  int*    cursor  = (int*)carve((size_t)N*4);
  int*    srcb    = (int*)carve((size_t)E*4);
  int*    dstb    = (int*)carve((size_t)E*4);
  int*    csr     = (int*)carve((size_t)E*4);
  ushort* x16     = (ushort*)carve((size_t)N*128*2);
  ushort* mean16  = (ushort*)carve((size_t)N*128*2);
  ushort* hskip16 = (ushort*)carve((size_t)N*128*2);
  ushort* wbuf    = (ushort*)carve((size_t)5*16384*2);
  float*  tbuf    = (float*)d_out;   // f32 GEMM output lives in d_out; ln_prelu in-place

  ushort* Wl0_16 = wbuf;
  ushort* Wr0_16 = wbuf + 16384;
  ushort* skW_16 = wbuf + 32768;
  ushort* Wl1_16 = wbuf + 49152;
  ushort* Wr1_16 = wbuf + 65536;

  hipMemsetAsync(stats, 0, 4*sizeof(double), stream);
  hipMemsetAsync(deg, 0, (size_t)N*4, stream);

  int eb = (E + 255)/256;
  int nb = (N + 4095)/4096;
  detect_fmt_kernel<<<1, 256, 0, stream>>>(ei, flag);
  extract_edges_kernel<<<eb, 256, 0, stream>>>(ei, E, flag, srcb, dstb, deg);
  convert_bf16_kernel<<<(N*16 + 255)/256, 256, 0, stream>>>(x, x16, N*16);
  convert_w_kernel<<<40, 256, 0, stream>>>(Wl0, Wr0, skW, Wl1, Wr1, wbuf);
  scan_part_kernel<<<nb, 256, 0, stream>>>(deg, bsum, N);
  scan_top_kernel<<<1, 64, 0, stream>>>(bsum, boff, nb);
  scan_out_kernel<<<nb, 256, 0, stream>>>(deg, boff, rowst, cursor, N);
  scatter_kernel<<<eb, 256, 0, stream>>>(srcb, dstb, cursor, csr, E);

  int ab  = (N + 3)/4;
  int gb  = (N + 127)/128;
  double inv_cnt = 1.0 / ((double)N * 128.0);

  // layer 0
  aggregate_kernel<<<ab, 256, 0, stream>>>(x16, csr, rowst, deg, mean16, N);
  gemm_dual_mfma<<<gb, 256, 0, stream>>>(mean16, x16, Wl0_16, Wr0_16, bl0, tbuf, N, stats);
  gemm_skip_mfma<<<gb, 256, 0, stream>>>(x16, skW_16, tbuf, stats, lnw0, lnb0, pw0, hskip16, N, inv_cnt);
  // layer 1
  aggregate_kernel<<<ab, 256, 0, stream>>>(hskip16, csr, rowst, deg, mean16, N);
  gemm_dual_mfma<<<gb, 256, 0, stream>>>(mean16, hskip16, Wl1_16, Wr1_16, bl1, tbuf, N, stats + 2);
  ln_prelu_kernel<<<2048, 256, 0, stream>>>(tbuf, stats + 2, lnw1, lnb1, pw1, (float*)d_out, N*32, inv_cnt);
}